// Round 9
// baseline (150.259 us; speedup 1.0000x reference)
//
#include <hip/hip_runtime.h>
#include <hip/hip_bf16.h>
#include <math.h>

#define SA_N 2048
#define SA_D 1024
#define SA_H 16
#define SA_HD 64

typedef __attribute__((ext_vector_type(8))) short bf16x8;
typedef __attribute__((ext_vector_type(4))) float f32x4;
typedef __attribute__((address_space(3))) void lds_t;
typedef __attribute__((address_space(1))) void gmem_t;

#define SC2 0.18033688011112042f   // (1/sqrt(64)) * log2(e), folded into Wq/bq

// ---------------- merged prep: x->bf16 and 4x W[K][N] -> bf16 Wt[N][K] ----------------
__global__ __launch_bounds__(256) void prep_kernel(
    const float* __restrict__ x,
    const float* __restrict__ Wq, const float* __restrict__ Wk,
    const float* __restrict__ Wv, const float* __restrict__ Wo,
    __hip_bfloat16* __restrict__ xbf, __hip_bfloat16* __restrict__ WtAll)
{
    const int tid = threadIdx.x;
    const int z = blockIdx.z;
    if (z < 2) {
        const int r = z * 1024 + blockIdx.y * 32 + (tid >> 3);
        const int c = blockIdx.x * 32 + (tid & 7) * 4;
        const size_t idx = (size_t)r * SA_D + c;
        float4 v = *reinterpret_cast<const float4*>(&x[idx]);
        union { __hip_bfloat16 hh[4]; short4 s4; } u;
        u.hh[0] = __float2bfloat16(v.x);
        u.hh[1] = __float2bfloat16(v.y);
        u.hh[2] = __float2bfloat16(v.z);
        u.hh[3] = __float2bfloat16(v.w);
        *reinterpret_cast<short4*>(&xbf[idx]) = u.s4;
    } else {
        const int w = z - 2;
        const float* W = (w == 0) ? Wq : (w == 1) ? Wk : (w == 2) ? Wv : Wo;
        const float scale = (w == 0) ? SC2 : 1.0f;
        __hip_bfloat16* Wt = WtAll + (size_t)w * SA_D * SA_D;
        __shared__ float t[32][33];
        const int c0 = blockIdx.x * 32, r0 = blockIdx.y * 32;
        const int tx = tid & 31, ty = tid >> 5;
#pragma unroll
        for (int p = 0; p < 4; ++p)
            t[ty + p * 8][tx] = W[(size_t)(r0 + ty + p * 8) * SA_D + c0 + tx] * scale;
        __syncthreads();
#pragma unroll
        for (int p = 0; p < 4; ++p)
            Wt[(size_t)(c0 + ty + p * 8) * SA_D + r0 + tx] =
                __float2bfloat16(t[tx][ty + p * 8]);
    }
}

// ---------------- bf16 MFMA GEMM 64x64 tile body (unchanged) ----------------
__device__ __forceinline__ void gemm_tile_body(
    const __hip_bfloat16* __restrict__ A,
    const __hip_bfloat16* __restrict__ Bt,
    const float* __restrict__ bias, float bias_scale,
    void* __restrict__ Cout, int mode, int M, int Kdim, int Nout,
    char* As, char* Bs)
{
    const int tid = threadIdx.x;
    const int wave = tid >> 6, lane = tid & 63;
    const int m = lane & 15, quad = lane >> 4;
    const int wm = wave >> 1, wn = wave & 1;
    const int row0 = blockIdx.y * 64, col0 = blockIdx.x * 64;

    f32x4 acc[2][2];
#pragma unroll
    for (int i = 0; i < 2; ++i)
#pragma unroll
        for (int j = 0; j < 2; ++j) acc[i][j] = (f32x4){0.f, 0.f, 0.f, 0.f};

    const int sr = tid >> 3;
    const int sc = tid & 7;

    for (int k0 = 0; k0 < Kdim; k0 += 64) {
#pragma unroll
        for (int p = 0; p < 2; ++p) {
            const int r = p * 32 + sr;
            const int pc = (sc ^ (r & 7)) * 16;
            const char* ga = (const char*)(A + (size_t)(row0 + r) * Kdim + k0) + pc;
            __builtin_amdgcn_global_load_lds((gmem_t*)ga,
                (lds_t*)(As + p * 4096 + wave * 1024), 16, 0, 0);
            const char* gb = (const char*)(Bt + (size_t)(col0 + r) * Kdim + k0) + pc;
            __builtin_amdgcn_global_load_lds((gmem_t*)gb,
                (lds_t*)(Bs + p * 4096 + wave * 1024), 16, 0, 0);
        }
        __syncthreads();

#pragma unroll
        for (int s = 0; s < 2; ++s) {
            bf16x8 af[2], bfr[2];
#pragma unroll
            for (int mi = 0; mi < 2; ++mi) {
                const int row = wm * 32 + mi * 16 + m;
                const int pc = (s * 4 + quad) ^ (row & 7);
                af[mi] = *reinterpret_cast<const bf16x8*>(As + row * 128 + pc * 16);
            }
#pragma unroll
            for (int ni = 0; ni < 2; ++ni) {
                const int col = wn * 32 + ni * 16 + m;
                const int pc = (s * 4 + quad) ^ (col & 7);
                bfr[ni] = *reinterpret_cast<const bf16x8*>(Bs + col * 128 + pc * 16);
            }
#pragma unroll
            for (int mi = 0; mi < 2; ++mi)
#pragma unroll
                for (int ni = 0; ni < 2; ++ni)
                    acc[mi][ni] = __builtin_amdgcn_mfma_f32_16x16x32_bf16(
                        af[mi], bfr[ni], acc[mi][ni], 0, 0, 0);
        }
        __syncthreads();
    }

#pragma unroll
    for (int ni = 0; ni < 2; ++ni) {
        const int col = col0 + wn * 32 + ni * 16 + m;
        const float bv = bias[col] * bias_scale;
#pragma unroll
        for (int mi = 0; mi < 2; ++mi) {
            const int rbase = row0 + wm * 32 + mi * 16 + quad * 4;
            if (mode == 0) {
#pragma unroll
                for (int reg = 0; reg < 4; ++reg)
                    ((float*)Cout)[(size_t)(rbase + reg) * Nout + col] =
                        acc[mi][ni][reg] + bv;
            } else if (mode == 1) {
#pragma unroll
                for (int reg = 0; reg < 4; ++reg)
                    ((__hip_bfloat16*)Cout)[(size_t)(rbase + reg) * Nout + col] =
                        __float2bfloat16(acc[mi][ni][reg] + bv);
            } else {
                union { __hip_bfloat16 hh[4]; short4 s4; } u;
#pragma unroll
                for (int reg = 0; reg < 4; ++reg)
                    u.hh[reg] = __float2bfloat16(acc[mi][ni][reg] + bv);
                *reinterpret_cast<short4*>(
                    &((__hip_bfloat16*)Cout)[(size_t)col * M + rbase]) = u.s4;
            }
        }
    }
}

__global__ __launch_bounds__(256) void gemm_qkv_kernel(
    const __hip_bfloat16* __restrict__ xbf, const __hip_bfloat16* __restrict__ WtAll,
    const float* __restrict__ bq, const float* __restrict__ bk, const float* __restrict__ bv,
    __hip_bfloat16* __restrict__ Qb, __hip_bfloat16* __restrict__ Kb,
    __hip_bfloat16* __restrict__ VtT)
{
    __shared__ __align__(16) char As[64 * 128];
    __shared__ __align__(16) char Bs[64 * 128];
    const int z = blockIdx.z;
    const __hip_bfloat16* Bt = WtAll + (size_t)z * SA_D * SA_D;
    const float* bias = (z == 0) ? bq : (z == 1) ? bk : bv;
    void* out = (z == 0) ? (void*)Qb : (z == 1) ? (void*)Kb : (void*)VtT;
    gemm_tile_body(xbf, Bt, bias, (z == 0) ? SC2 : 1.0f, out,
                   (z == 2) ? 2 : 1, SA_N, SA_D, SA_D, As, Bs);
}

__global__ __launch_bounds__(256) void gemm_out_kernel(
    const __hip_bfloat16* __restrict__ Abf, const __hip_bfloat16* __restrict__ Wt,
    const float* __restrict__ bo, float* __restrict__ out)
{
    __shared__ __align__(16) char As[64 * 128];
    __shared__ __align__(16) char Bs[64 * 128];
    gemm_tile_body(Abf, Wt, bo, 1.0f, out, 0, SA_N, SA_D, SA_D, As, Bs);
}

// ---------------- MFMA flash attention v5: split-K groups + Q in registers ----------------
// v4 + : Qs LDS array deleted. Each wave's A-fragment of Q is, per the verified
// 16x16x32 layout, a contiguous 16 B global read:
//   Qb[row0 + w4*16 + (lane&15)][h*64 + s*32 + (lane>>4)*8]
// loaded ONCE into 2 bf16x8 regs (L2-hot). LDS: Ks 16K + Vs 16K + Ps 2x9K + l 256B
// = 50.25 KB -> 3 blocks/CU = 6 waves/SIMD (was 2 blocks / 4 waves).
// __launch_bounds__(512,6) caps VGPR at 84 to guarantee it.
__global__ __launch_bounds__(512, 6) void flash_mfma_kernel(
    const __hip_bfloat16* __restrict__ Qb,  // [N][D], pre-scaled by SC2
    const __hip_bfloat16* __restrict__ Kb,  // [N][D]
    const __hip_bfloat16* __restrict__ Vt,  // [D][N]
    __hip_bfloat16* __restrict__ O)         // [N][D]
{
    const int b = blockIdx.x;
    const int h = b & 15;
    const int qraw = b >> 4;
    const int qt = (qraw < 16) ? qraw : 47 - qraw;  // fold for CU balance
    const int row0 = qt * 64;
    const int ntiles = (qt >> 1) + 1;               // 128-key tiles

    const int tid = threadIdx.x;
    const int wave = tid >> 6, lane = tid & 63;
    const int g = wave >> 2, w4 = wave & 3;         // group, wave-in-group
    const int ln = lane & 15, quad = lane >> 4;

    __shared__ __align__(16) char Ks[128 * 128];    // [key][dim] bf16 (reused as fp32 merge buf)
    __shared__ __align__(16) char Vs[64 * 256];     // [dim][key] bf16, 128 keys/row
    __shared__ __align__(16) char Ps[2][64 * 144];  // per-group [qrow][key] bf16
    __shared__ float lmerge[64];

    // Q A-fragments directly to registers (one-time, L2-hot)
    bf16x8 qf[2];
#pragma unroll
    for (int s = 0; s < 2; ++s)
        qf[s] = *reinterpret_cast<const bf16x8*>(
            Qb + (size_t)(row0 + w4 * 16 + ln) * SA_D + h * SA_HD + s * 32 + quad * 8);

    f32x4 oacc[4], lacc;
#pragma unroll
    for (int dg = 0; dg < 4; ++dg) oacc[dg] = (f32x4){0.f, 0.f, 0.f, 0.f};
    lacc = (f32x4){0.f, 0.f, 0.f, 0.f};

    const short one_bf = (short)0x3F80;
    const bf16x8 ones = {one_bf, one_bf, one_bf, one_bf, one_bf, one_bf, one_bf, one_bf};

    for (int kt = 0; kt < ntiles; ++kt) {
        __syncthreads();   // all waves done reading Ks/Vs from prev iter
        // stage K: 128 rows x 8 chunks, 2 rounds (8 waves cover 64 rows/round)
#pragma unroll
        for (int p = 0; p < 2; ++p) {
            const int r = p * 64 + wave * 8 + (lane >> 3);
            const int pc = ((lane & 7) ^ (r & 7)) * 16;
            const char* gk = (const char*)(Kb + (size_t)(kt * 128 + r) * SA_D + h * SA_HD) + pc;
            __builtin_amdgcn_global_load_lds((gmem_t*)gk,
                (lds_t*)(Ks + p * 8192 + wave * 1024), 16, 0, 0);
        }
        // stage V: 64 rows x 16 chunks, 2 rounds (8 waves cover 32 rows/round)
#pragma unroll
        for (int p = 0; p < 2; ++p) {
            const int r = p * 32 + wave * 4 + (lane >> 4);
            const int pc = ((lane & 15) ^ (r & 15)) * 16;
            const char* gv = (const char*)(Vt + (size_t)(h * SA_HD + r) * SA_N + kt * 128) + pc;
            __builtin_amdgcn_global_load_lds((gmem_t*)gv,
                (lds_t*)(Vs + p * 8192 + wave * 1024), 16, 0, 0);
        }
        __syncthreads();   // staged data visible (vmcnt drained at barrier)

        // S = Q K^T : wave's 16 q-rows x group's 64 keys
        f32x4 sacc[4];
#pragma unroll
        for (int gg = 0; gg < 4; ++gg) sacc[gg] = (f32x4){0.f, 0.f, 0.f, 0.f};
#pragma unroll
        for (int s = 0; s < 2; ++s) {
#pragma unroll
            for (int gg = 0; gg < 4; ++gg) {
                const int krow = g * 64 + gg * 16 + ln;
                const int pcb = (s * 4 + quad) ^ (krow & 7);
                bf16x8 bf = *reinterpret_cast<const bf16x8*>(Ks + krow * 128 + pcb * 16);
                sacc[gg] = __builtin_amdgcn_mfma_f32_16x16x32_bf16(qf[s], bf, sacc[gg], 0, 0, 0);
            }
        }

        // P = exp2(S) + causal mask (only last tile straddles/exceeds diagonal)
        const bool last = (kt == ntiles - 1);
        const int prow_b = w4 * 16 + quad * 4;
        const int qrow_b = row0 + prow_b;
        char* Pg = Ps[g];
#pragma unroll
        for (int gg = 0; gg < 4; ++gg) {
            const int key = kt * 128 + g * 64 + gg * 16 + ln;
#pragma unroll
            for (int reg = 0; reg < 4; ++reg) {
                float p = exp2f(sacc[gg][reg]);
                if (last && key > (qrow_b + reg)) p = 0.f;
                *reinterpret_cast<__hip_bfloat16*>(
                    Pg + (prow_b + reg) * 144 + (gg * 16 + ln) * 2) = __float2bfloat16(p);
            }
        }

        // O += P V ; l += P . ones   (V columns of this group's keys)
#pragma unroll
        for (int s2 = 0; s2 < 2; ++s2) {
            bf16x8 pf = *reinterpret_cast<const bf16x8*>(
                Pg + (w4 * 16 + ln) * 144 + s2 * 64 + quad * 16);
            lacc = __builtin_amdgcn_mfma_f32_16x16x32_bf16(pf, ones, lacc, 0, 0, 0);
#pragma unroll
            for (int dg = 0; dg < 4; ++dg) {
                const int vrow = dg * 16 + ln;
                const int kc = g * 8 + s2 * 4 + quad;       // key-chunk within 128-key row
                const int pcb = (kc ^ (vrow & 15)) * 16;
                bf16x8 vf = *reinterpret_cast<const bf16x8*>(Vs + vrow * 256 + pcb);
                oacc[dg] = __builtin_amdgcn_mfma_f32_16x16x32_bf16(pf, vf, oacc[dg], 0, 0, 0);
            }
        }
    }

    // merge groups: group 1 dumps fp32 partials into Ks (16 KB = 64x64 f32)
    __syncthreads();
    float* Kf = reinterpret_cast<float*>(Ks);
    if (g == 1) {
#pragma unroll
        for (int reg = 0; reg < 4; ++reg) {
            const int row = w4 * 16 + quad * 4 + reg;
#pragma unroll
            for (int dg = 0; dg < 4; ++dg)
                Kf[row * 64 + dg * 16 + ln] = oacc[dg][reg];
            if (ln == 0) lmerge[row] = lacc[reg];
        }
    }
    __syncthreads();
    if (g == 0) {
#pragma unroll
        for (int reg = 0; reg < 4; ++reg) {
            const int row = w4 * 16 + quad * 4 + reg;
            const float inv = 1.0f / (lacc[reg] + lmerge[row]);
            const int qrow = row0 + row;
#pragma unroll
            for (int dg = 0; dg < 4; ++dg)
                O[(size_t)qrow * SA_D + h * SA_HD + dg * 16 + ln] =
                    __float2bfloat16((oacc[dg][reg] + Kf[row * 64 + dg * 16 + ln]) * inv);
        }
    }
}

extern "C" void kernel_launch(void* const* d_in, const int* in_sizes, int n_in,
                              void* d_out, int out_size, void* d_ws, size_t ws_size,
                              hipStream_t stream) {
    const float* x  = (const float*)d_in[0];
    const float* Wq = (const float*)d_in[1];
    const float* bq = (const float*)d_in[2];
    const float* Wk = (const float*)d_in[3];
    const float* bk = (const float*)d_in[4];
    const float* Wv = (const float*)d_in[5];
    const float* bv = (const float*)d_in[6];
    const float* Wo = (const float*)d_in[7];
    const float* bo = (const float*)d_in[8];
    float* out = (float*)d_out;

    const size_t ND = (size_t)SA_N * SA_D;
    const size_t DD = (size_t)SA_D * SA_D;
    __hip_bfloat16* xbf   = (__hip_bfloat16*)d_ws;
    __hip_bfloat16* WtAll = xbf + ND;
    __hip_bfloat16* Qb    = WtAll + 4 * DD;
    __hip_bfloat16* Kb    = Qb + ND;
    __hip_bfloat16* VtT   = Kb + ND;
    __hip_bfloat16* Abf   = VtT + ND;

    prep_kernel<<<dim3(32, 32, 6), 256, 0, stream>>>(x, Wq, Wk, Wv, Wo, xbf, WtAll);
    gemm_qkv_kernel<<<dim3(SA_D / 64, SA_N / 64, 3), 256, 0, stream>>>(
        xbf, WtAll, bq, bk, bv, Qb, Kb, VtT);
    flash_mfma_kernel<<<dim3(512), 512, 0, stream>>>(Qb, Kb, VtT, Abf);
    gemm_out_kernel<<<dim3(SA_D / 64, SA_N / 64), 256, 0, stream>>>(
        Abf, WtAll + 3 * DD, bo, out);
}